// Round 5
// baseline (318.467 us; speedup 1.0000x reference)
//
#include <hip/hip_runtime.h>

#define N_NODES 50000
#define N_EDGES 800000
#define D_HID   128

typedef unsigned int uint;
typedef unsigned short ushort;
typedef __attribute__((ext_vector_type(8))) short short8;
typedef __attribute__((ext_vector_type(4))) float f32x4;

#define SCAN_NB ((N_NODES + 255) / 256)   // 196

// ---------------- degree count ----------------
__global__ void deg_count_k(const int* __restrict__ dst, int* __restrict__ cnt, int e) {
    int i = blockIdx.x * 256 + threadIdx.x;
    if (i < e) atomicAdd(&cnt[dst[i]], 1);
}

// ---------------- degree -> dis / dinv ----------------
__global__ void deg_norm_k(const int* __restrict__ cnt, float* __restrict__ dis,
                           float* __restrict__ dinv, int n) {
    int i = blockIdx.x * 256 + threadIdx.x;
    if (i < n) {
        float d = (float)cnt[i] + 1.0f;
        dis[i]  = rsqrtf(d);
        dinv[i] = 1.0f / d;
    }
}

// ---------------- 3-phase multi-block exclusive scan ----------------
__global__ void bsum_k(const int* __restrict__ cnt, int* __restrict__ bsum, int n) {
    int i = blockIdx.x * 256 + threadIdx.x;
    int v = (i < n) ? cnt[i] : 0;
#pragma unroll
    for (int off = 32; off; off >>= 1) v += __shfl_down(v, off, 64);
    __shared__ int ws[4];
    int lane = threadIdx.x & 63, w = threadIdx.x >> 6;
    if (lane == 0) ws[w] = v;
    __syncthreads();
    if (threadIdx.x == 0) bsum[blockIdx.x] = ws[0] + ws[1] + ws[2] + ws[3];
}

__global__ void bscan_k(const int* __restrict__ bsum, int* __restrict__ boff,
                        int* __restrict__ row_ptr_end, int nb) {
    __shared__ int s[256];
    int t = threadIdx.x;
    int v = (t < nb) ? bsum[t] : 0;
    s[t] = v;
    __syncthreads();
    for (int off = 1; off < 256; off <<= 1) {
        int u = (t >= off) ? s[t - off] : 0;
        __syncthreads();
        s[t] += u;
        __syncthreads();
    }
    if (t < nb) boff[t] = s[t] - v;        // exclusive
    if (t == 255) *row_ptr_end = s[255];   // total -> row_ptr[n]
}

__global__ void scan3_k(const int* __restrict__ cnt, const int* __restrict__ boff,
                        int* __restrict__ row_ptr, int n) {
    __shared__ int s[256];
    int i = blockIdx.x * 256 + threadIdx.x;
    int t = threadIdx.x;
    int v = (i < n) ? cnt[i] : 0;
    s[t] = v;
    __syncthreads();
    for (int off = 1; off < 256; off <<= 1) {
        int u = (t >= off) ? s[t - off] : 0;
        __syncthreads();
        s[t] += u;
        __syncthreads();
    }
    if (i < n) row_ptr[i] = boff[blockIdx.x] + s[t] - v;
}

// ---------------- scatter edges into CSR (packed col+weight, single 8B write) ----------------
__global__ void scatter_k(const int* __restrict__ src, const int* __restrict__ dst,
                          const int* __restrict__ row_ptr, int* __restrict__ cursor,
                          int2* __restrict__ cew,
                          const float* __restrict__ dis, int e) {
    int i = blockIdx.x * 256 + threadIdx.x;
    if (i < e) {
        int s = src[i], d = dst[i];
        int pos = row_ptr[d] + atomicAdd(&cursor[d], 1);
        cew[pos] = make_int2(s, __float_as_int(dis[s]));
    }
}

// ---- fp32 -> bf16 (RTNE) ----
__device__ inline ushort f2bf(float f) {
    unsigned u = __float_as_uint(f);
    unsigned rounding = 0x7fffu + ((u >> 16) & 1u);
    return (ushort)((u + rounding) >> 16);
}

// ---------------- W[K][128] fp32 -> Wt[128][K] bf16 ----------------
__global__ void wtrans_k(const float* __restrict__ W, ushort* __restrict__ Wt, int K) {
    int i = blockIdx.x * 256 + threadIdx.x;
    if (i < K * 128) {
        int k = i >> 7, n = i & 127;
        Wt[(size_t)n * K + k] = f2bf(W[i]);
    }
}

// ---------------- MFMA GEMM: H[M x 128](bf16) = A[M x K] * Wt^T ----------------
template<int K, bool AF32>
__global__ __launch_bounds__(256) void mfma_gemm_k(const void* __restrict__ Ap,
                                                   const ushort* __restrict__ Bt, // [128][K] bf16
                                                   ushort* __restrict__ H,        // [M][128] bf16
                                                   int M) {
    int tid = threadIdx.x;
    int w   = tid >> 6;
    int l   = tid & 63;
    int row = blockIdx.x * 64 + w * 16 + (l & 15);
    int rc  = row < M ? row : M - 1;
    int kg  = (l >> 4) * 8;

    const ushort* A16 = (const ushort*)Ap;
    const float*  A32 = (const float*)Ap;

    f32x4 acc[8];
#pragma unroll
    for (int c = 0; c < 8; ++c) acc[c] = (f32x4){0.f, 0.f, 0.f, 0.f};

#pragma unroll
    for (int k0 = 0; k0 < K; k0 += 32) {
        short8 a;
        if (AF32) {
            const float* ap = &A32[(size_t)rc * K + k0 + kg];
            float4 f0 = *(const float4*)ap;
            float4 f1 = *(const float4*)(ap + 4);
            a[0] = (short)f2bf(f0.x); a[1] = (short)f2bf(f0.y);
            a[2] = (short)f2bf(f0.z); a[3] = (short)f2bf(f0.w);
            a[4] = (short)f2bf(f1.x); a[5] = (short)f2bf(f1.y);
            a[6] = (short)f2bf(f1.z); a[7] = (short)f2bf(f1.w);
        } else {
            a = *(const short8*)&A16[(size_t)rc * K + k0 + kg];
        }
#pragma unroll
        for (int c = 0; c < 8; ++c) {
            short8 b = *(const short8*)&Bt[(size_t)(c * 16 + (l & 15)) * K + k0 + kg];
            acc[c] = __builtin_amdgcn_mfma_f32_16x16x32_bf16(a, b, acc[c], 0, 0, 0);
        }
    }

    int r_base = blockIdx.x * 64 + w * 16 + (l >> 4) * 4;
    int colb   = l & 15;
#pragma unroll
    for (int c = 0; c < 8; ++c) {
#pragma unroll
        for (int j = 0; j < 4; ++j) {
            int r = r_base + j;
            if (r < M) H[(size_t)r * 128 + c * 16 + colb] = f2bf(acc[c][j]);
        }
    }
}

// ---------------- aggregate: relu(dis[n]*sum_e(w*hb[s]) + hb[n]*dinv[n] + b) ----------------
template<bool LAST>
__global__ __launch_bounds__(256) void aggregate_k(const ushort* __restrict__ hb,
                                                   const int* __restrict__ row_ptr,
                                                   const int2* __restrict__ cew,
                                                   const float* __restrict__ dis,
                                                   const float* __restrict__ dinv,
                                                   const float* __restrict__ bias,
                                                   ushort* __restrict__ act,
                                                   float* __restrict__ out, int n) {
    int node = blockIdx.x * 4 + (threadIdx.x >> 6);
    if (node >= n) return;
    int lane = threadIdx.x & 63;
    const char* base = (const char*)hb + (lane << 2);   // lane*4 bytes, row stride 256B

    float ax = 0.f, ay = 0.f;
    int beg = row_ptr[node], end = row_ptr[node + 1];
    for (int e = beg; e < end; e += 8) {
        int   s[8]; float wv[8];
#pragma unroll
        for (int q = 0; q < 8; ++q) {
            int idx = e + q;
            bool v  = idx < end;
            int2 p  = cew[v ? idx : (end - 1)];
            s[q]  = p.x;
            wv[q] = v ? __int_as_float(p.y) : 0.f;
        }
        uint u[8];
#pragma unroll
        for (int q = 0; q < 8; ++q)
            u[q] = *(const uint*)(base + ((size_t)s[q] << 8));
#pragma unroll
        for (int q = 0; q < 8; ++q) {
            ax += wv[q] * __uint_as_float(u[q] << 16);
            ay += wv[q] * __uint_as_float(u[q] & 0xffff0000u);
        }
    }
    float dn = dis[node], di = dinv[node];
    uint un = *(const uint*)(base + ((size_t)node << 8));
    float hx = __uint_as_float(un << 16);
    float hy = __uint_as_float(un & 0xffff0000u);
    int c0 = lane * 2;
    float2 bv = *(const float2*)&bias[c0];
    float ox = fmaxf(ax * dn + hx * di + bv.x, 0.f);
    float oy = fmaxf(ay * dn + hy * di + bv.y, 0.f);
    if (LAST) {
        *(float2*)&out[(size_t)node * D_HID + c0] = make_float2(ox, oy);
    } else {
        uint p = (uint)f2bf(ox) | ((uint)f2bf(oy) << 16);
        *(uint*)((char*)act + ((size_t)node << 8) + (lane << 2)) = p;
    }
}

extern "C" void kernel_launch(void* const* d_in, const int* in_sizes, int n_in,
                              void* d_out, int out_size, void* d_ws, size_t ws_size,
                              hipStream_t stream) {
    const float* x  = (const float*)d_in[0];
    const int*   ei = (const int*)d_in[1];
    const float* W0 = (const float*)d_in[2];
    const float* b0 = (const float*)d_in[3];
    const float* W1 = (const float*)d_in[4];
    const float* b1 = (const float*)d_in[5];
    const float* W2 = (const float*)d_in[6];
    const float* b2 = (const float*)d_in[7];
    float* out = (float*)d_out;

    const int N = N_NODES, E = N_EDGES;
    const int* src = ei;
    const int* dst = ei + E;

    char* w = (char*)d_ws;
    size_t off = 0;
    auto alloc = [&](size_t bytes) {
        size_t o = off;
        off += (bytes + 255) & ~(size_t)255;
        return o;
    };
    int*    cnt    = (int*)(w + alloc((size_t)N * 4));
    int*    cursor = (int*)(w + alloc((size_t)N * 4));
    float*  dis    = (float*)(w + alloc((size_t)N * 4));
    float*  dinv   = (float*)(w + alloc((size_t)N * 4));
    int*    rp     = (int*)(w + alloc((size_t)(N + 1) * 4));
    int*    bsum   = (int*)(w + alloc((size_t)SCAN_NB * 4));
    int*    boff   = (int*)(w + alloc((size_t)SCAN_NB * 4));
    int2*   cew    = (int2*)(w + alloc((size_t)E * 8));
    ushort* hb     = (ushort*)(w + alloc((size_t)N * D_HID * 2));
    ushort* act    = (ushort*)(w + alloc((size_t)N * D_HID * 2));
    ushort* Wt0    = (ushort*)(w + alloc((size_t)128 * 256 * 2));
    ushort* Wt1    = (ushort*)(w + alloc((size_t)128 * 128 * 2));
    ushort* Wt2    = (ushort*)(w + alloc((size_t)128 * 128 * 2));
    (void)ws_size; (void)n_in; (void)in_sizes; (void)out_size;

    hipMemsetAsync(cnt, 0, (size_t)N * 4, stream);
    hipMemsetAsync(cursor, 0, (size_t)N * 4, stream);

    deg_count_k<<<(E + 255) / 256, 256, 0, stream>>>(dst, cnt, E);
    deg_norm_k<<<(N + 255) / 256, 256, 0, stream>>>(cnt, dis, dinv, N);
    bsum_k<<<SCAN_NB, 256, 0, stream>>>(cnt, bsum, N);
    bscan_k<<<1, 256, 0, stream>>>(bsum, boff, rp + N, SCAN_NB);
    scan3_k<<<SCAN_NB, 256, 0, stream>>>(cnt, boff, rp, N);
    scatter_k<<<(E + 255) / 256, 256, 0, stream>>>(src, dst, rp, cursor, cew, dis, E);

    wtrans_k<<<(256 * 128 + 255) / 256, 256, 0, stream>>>(W0, Wt0, 256);
    wtrans_k<<<(128 * 128 + 255) / 256, 256, 0, stream>>>(W1, Wt1, 128);
    wtrans_k<<<(128 * 128 + 255) / 256, 256, 0, stream>>>(W2, Wt2, 128);

    int gemm_grid = (N + 63) / 64;
    int agg_grid  = (N + 3) / 4;

    // layer 0
    mfma_gemm_k<256, true><<<gemm_grid, 256, 0, stream>>>(x, Wt0, hb, N);
    aggregate_k<false><<<agg_grid, 256, 0, stream>>>(hb, rp, cew, dis, dinv, b0, act, out, N);
    // layer 1
    mfma_gemm_k<128, false><<<gemm_grid, 256, 0, stream>>>(act, Wt1, hb, N);
    aggregate_k<false><<<agg_grid, 256, 0, stream>>>(hb, rp, cew, dis, dinv, b1, act, out, N);
    // layer 2
    mfma_gemm_k<128, false><<<gemm_grid, 256, 0, stream>>>(act, Wt2, hb, N);
    aggregate_k<true><<<agg_grid, 256, 0, stream>>>(hb, rp, cew, dis, dinv, b2, act, out, N);
}

// Round 6
// 275.678 us; speedup vs baseline: 1.1552x; 1.1552x over previous
//
#include <hip/hip_runtime.h>

#define N_NODES 50000
#define N_EDGES 800000
#define D_HID   128

typedef unsigned int uint;
typedef unsigned short ushort;
typedef __attribute__((ext_vector_type(8))) short short8;
typedef __attribute__((ext_vector_type(4))) float f32x4;

#define SCAN_NB ((N_NODES + 255) / 256)   // 196

// ---------------- degree count ----------------
__global__ void deg_count_k(const int* __restrict__ dst, int* __restrict__ cnt, int e) {
    int i = blockIdx.x * 256 + threadIdx.x;
    if (i < e) atomicAdd(&cnt[dst[i]], 1);
}

// ---------------- 3-phase multi-block exclusive scan ----------------
__global__ void bsum_k(const int* __restrict__ cnt, int* __restrict__ bsum, int n) {
    int i = blockIdx.x * 256 + threadIdx.x;
    int v = (i < n) ? cnt[i] : 0;
#pragma unroll
    for (int off = 32; off; off >>= 1) v += __shfl_down(v, off, 64);
    __shared__ int ws[4];
    int lane = threadIdx.x & 63, w = threadIdx.x >> 6;
    if (lane == 0) ws[w] = v;
    __syncthreads();
    if (threadIdx.x == 0) bsum[blockIdx.x] = ws[0] + ws[1] + ws[2] + ws[3];
}

__global__ void bscan_k(const int* __restrict__ bsum, int* __restrict__ boff,
                        int* __restrict__ row_ptr_end, int nb) {
    __shared__ int s[256];
    int t = threadIdx.x;
    int v = (t < nb) ? bsum[t] : 0;
    s[t] = v;
    __syncthreads();
    for (int off = 1; off < 256; off <<= 1) {
        int u = (t >= off) ? s[t - off] : 0;
        __syncthreads();
        s[t] += u;
        __syncthreads();
    }
    if (t < nb) boff[t] = s[t] - v;        // exclusive
    if (t == 255) *row_ptr_end = s[255];   // total -> row_ptr[n]
}

// scan + fused degree-norm + cursor zeroing
__global__ void scan3_k(const int* __restrict__ cnt, const int* __restrict__ boff,
                        int* __restrict__ row_ptr, float* __restrict__ dis,
                        float* __restrict__ dinv, int* __restrict__ cursor, int n) {
    __shared__ int s[256];
    int i = blockIdx.x * 256 + threadIdx.x;
    int t = threadIdx.x;
    int v = (i < n) ? cnt[i] : 0;
    s[t] = v;
    __syncthreads();
    for (int off = 1; off < 256; off <<= 1) {
        int u = (t >= off) ? s[t - off] : 0;
        __syncthreads();
        s[t] += u;
        __syncthreads();
    }
    if (i < n) {
        row_ptr[i] = boff[blockIdx.x] + s[t] - v;
        float d = (float)v + 1.0f;
        dis[i]  = rsqrtf(d);
        dinv[i] = 1.0f / d;
        cursor[i] = 0;
    }
}

// ---------------- scatter edges into CSR (packed col+weight, single 8B write) ----------------
__global__ void scatter_k(const int* __restrict__ src, const int* __restrict__ dst,
                          const int* __restrict__ row_ptr, int* __restrict__ cursor,
                          int2* __restrict__ cew,
                          const float* __restrict__ dis, int e) {
    int i = blockIdx.x * 256 + threadIdx.x;
    if (i < e) {
        int s = src[i], d = dst[i];
        int pos = row_ptr[d] + atomicAdd(&cursor[d], 1);
        cew[pos] = make_int2(s, __float_as_int(dis[s]));
    }
}

// ---- fp32 -> bf16 (RTNE) ----
__device__ inline ushort f2bf(float f) {
    unsigned u = __float_as_uint(f);
    unsigned rounding = 0x7fffu + ((u >> 16) & 1u);
    return (ushort)((u + rounding) >> 16);
}
__device__ inline float bf_lo(uint v) { return __uint_as_float(v << 16); }
__device__ inline float bf_hi(uint v) { return __uint_as_float(v & 0xffff0000u); }

// ---------------- all three W[K][128] fp32 -> Wt[128][K] bf16, one launch ----------------
__global__ void wtrans_all_k(const float* __restrict__ W0, const float* __restrict__ W1,
                             const float* __restrict__ W2, ushort* __restrict__ Wt0,
                             ushort* __restrict__ Wt1, ushort* __restrict__ Wt2) {
    int i = blockIdx.x * 256 + threadIdx.x;   // 0..65535
    const float* W; ushort* Wt; int K, j;
    if (i < 32768)      { W = W0; Wt = Wt0; K = 256; j = i; }
    else if (i < 49152) { W = W1; Wt = Wt1; K = 128; j = i - 32768; }
    else                { W = W2; Wt = Wt2; K = 128; j = i - 49152; }
    int k = j >> 7, n = j & 127;
    Wt[(size_t)n * K + k] = f2bf(W[j]);
}

// ---------------- MFMA GEMM: H[M x 128](bf16) = A[M x K] * Wt^T ----------------
template<int K, bool AF32>
__global__ __launch_bounds__(256) void mfma_gemm_k(const void* __restrict__ Ap,
                                                   const ushort* __restrict__ Bt, // [128][K] bf16
                                                   ushort* __restrict__ H,        // [M][128] bf16
                                                   int M) {
    int tid = threadIdx.x;
    int w   = tid >> 6;
    int l   = tid & 63;
    int row = blockIdx.x * 64 + w * 16 + (l & 15);
    int rc  = row < M ? row : M - 1;
    int kg  = (l >> 4) * 8;

    const ushort* A16 = (const ushort*)Ap;
    const float*  A32 = (const float*)Ap;

    f32x4 acc[8];
#pragma unroll
    for (int c = 0; c < 8; ++c) acc[c] = (f32x4){0.f, 0.f, 0.f, 0.f};

#pragma unroll
    for (int k0 = 0; k0 < K; k0 += 32) {
        short8 a;
        if (AF32) {
            const float* ap = &A32[(size_t)rc * K + k0 + kg];
            float4 f0 = *(const float4*)ap;
            float4 f1 = *(const float4*)(ap + 4);
            a[0] = (short)f2bf(f0.x); a[1] = (short)f2bf(f0.y);
            a[2] = (short)f2bf(f0.z); a[3] = (short)f2bf(f0.w);
            a[4] = (short)f2bf(f1.x); a[5] = (short)f2bf(f1.y);
            a[6] = (short)f2bf(f1.z); a[7] = (short)f2bf(f1.w);
        } else {
            a = *(const short8*)&A16[(size_t)rc * K + k0 + kg];
        }
#pragma unroll
        for (int c = 0; c < 8; ++c) {
            short8 b = *(const short8*)&Bt[(size_t)(c * 16 + (l & 15)) * K + k0 + kg];
            acc[c] = __builtin_amdgcn_mfma_f32_16x16x32_bf16(a, b, acc[c], 0, 0, 0);
        }
    }

    int r_base = blockIdx.x * 64 + w * 16 + (l >> 4) * 4;
    int colb   = l & 15;
#pragma unroll
    for (int c = 0; c < 8; ++c) {
#pragma unroll
        for (int j = 0; j < 4; ++j) {
            int r = r_base + j;
            if (r < M) H[(size_t)r * 128 + c * 16 + colb] = f2bf(acc[c][j]);
        }
    }
}

// ---------------- aggregate: relu(dis[n]*sum_e(w*hb[s]) + hb[n]*dinv[n] + b) ----------------
// uint4 gathers: 16 lanes cover one 256B row -> 4 edges per load instruction.
// lane = g*16 + cl : g = edge slot (0..3), cl = column block (8 cols each).
template<bool LAST>
__global__ __launch_bounds__(256) void aggregate_k(const ushort* __restrict__ hb,
                                                   const int* __restrict__ row_ptr,
                                                   const int2* __restrict__ cew,
                                                   const float* __restrict__ dis,
                                                   const float* __restrict__ dinv,
                                                   const float* __restrict__ bias,
                                                   ushort* __restrict__ act,
                                                   float* __restrict__ out, int n) {
    int node = blockIdx.x * 4 + (threadIdx.x >> 6);
    if (node >= n) return;
    int lane = threadIdx.x & 63;
    int g  = lane >> 4;          // edge-slot group 0..3
    int cl = lane & 15;          // column block: cols [8*cl, 8*cl+8)
    const char* base = (const char*)hb + (cl << 4);   // cl*16 bytes within row

    float ax[8];
#pragma unroll
    for (int j = 0; j < 8; ++j) ax[j] = 0.f;

    int beg = row_ptr[node], end = row_ptr[node + 1];
    for (int e = beg; e < end; e += 16) {
        int s[4]; float wv[4];
#pragma unroll
        for (int q = 0; q < 4; ++q) {
            int idx = e + q * 4 + g;
            bool v  = idx < end;
            int2 p  = cew[v ? idx : (end - 1)];
            s[q]  = p.x;
            wv[q] = v ? __int_as_float(p.y) : 0.f;
        }
        uint4 u[4];
#pragma unroll
        for (int q = 0; q < 4; ++q)
            u[q] = *(const uint4*)(base + ((size_t)s[q] << 8));
#pragma unroll
        for (int q = 0; q < 4; ++q) {
            float ww = wv[q];
            ax[0] += ww * bf_lo(u[q].x); ax[1] += ww * bf_hi(u[q].x);
            ax[2] += ww * bf_lo(u[q].y); ax[3] += ww * bf_hi(u[q].y);
            ax[4] += ww * bf_lo(u[q].z); ax[5] += ww * bf_hi(u[q].z);
            ax[6] += ww * bf_lo(u[q].w); ax[7] += ww * bf_hi(u[q].w);
        }
    }
    // combine the 4 edge-slot groups (lanes cl, cl+16, cl+32, cl+48 share columns)
#pragma unroll
    for (int j = 0; j < 8; ++j) {
        ax[j] += __shfl_xor(ax[j], 16);
        ax[j] += __shfl_xor(ax[j], 32);
    }
    if (g == 0) {
        float dn = dis[node], di = dinv[node];
        uint4 un = *(const uint4*)(base + ((size_t)node << 8));
        float hs[8] = {bf_lo(un.x), bf_hi(un.x), bf_lo(un.y), bf_hi(un.y),
                       bf_lo(un.z), bf_hi(un.z), bf_lo(un.w), bf_hi(un.w)};
        int c0 = cl * 8;
        float4 bv0 = *(const float4*)&bias[c0];
        float4 bv1 = *(const float4*)&bias[c0 + 4];
        float bb[8] = {bv0.x, bv0.y, bv0.z, bv0.w, bv1.x, bv1.y, bv1.z, bv1.w};
        float o[8];
#pragma unroll
        for (int j = 0; j < 8; ++j)
            o[j] = fmaxf(ax[j] * dn + hs[j] * di + bb[j], 0.f);
        if (LAST) {
            *(float4*)&out[(size_t)node * D_HID + c0]     = make_float4(o[0], o[1], o[2], o[3]);
            *(float4*)&out[(size_t)node * D_HID + c0 + 4] = make_float4(o[4], o[5], o[6], o[7]);
        } else {
            uint4 p;
            p.x = (uint)f2bf(o[0]) | ((uint)f2bf(o[1]) << 16);
            p.y = (uint)f2bf(o[2]) | ((uint)f2bf(o[3]) << 16);
            p.z = (uint)f2bf(o[4]) | ((uint)f2bf(o[5]) << 16);
            p.w = (uint)f2bf(o[6]) | ((uint)f2bf(o[7]) << 16);
            *(uint4*)((char*)act + ((size_t)node << 8) + (cl << 4)) = p;
        }
    }
}

extern "C" void kernel_launch(void* const* d_in, const int* in_sizes, int n_in,
                              void* d_out, int out_size, void* d_ws, size_t ws_size,
                              hipStream_t stream) {
    const float* x  = (const float*)d_in[0];
    const int*   ei = (const int*)d_in[1];
    const float* W0 = (const float*)d_in[2];
    const float* b0 = (const float*)d_in[3];
    const float* W1 = (const float*)d_in[4];
    const float* b1 = (const float*)d_in[5];
    const float* W2 = (const float*)d_in[6];
    const float* b2 = (const float*)d_in[7];
    float* out = (float*)d_out;

    const int N = N_NODES, E = N_EDGES;
    const int* src = ei;
    const int* dst = ei + E;

    char* w = (char*)d_ws;
    size_t off = 0;
    auto alloc = [&](size_t bytes) {
        size_t o = off;
        off += (bytes + 255) & ~(size_t)255;
        return o;
    };
    int*    cnt    = (int*)(w + alloc((size_t)N * 4));
    int*    cursor = (int*)(w + alloc((size_t)N * 4));
    float*  dis    = (float*)(w + alloc((size_t)N * 4));
    float*  dinv   = (float*)(w + alloc((size_t)N * 4));
    int*    rp     = (int*)(w + alloc((size_t)(N + 1) * 4));
    int*    bsum   = (int*)(w + alloc((size_t)SCAN_NB * 4));
    int*    boff   = (int*)(w + alloc((size_t)SCAN_NB * 4));
    int2*   cew    = (int2*)(w + alloc((size_t)E * 8));
    ushort* hb     = (ushort*)(w + alloc((size_t)N * D_HID * 2));
    ushort* act    = (ushort*)(w + alloc((size_t)N * D_HID * 2));
    ushort* Wt0    = (ushort*)(w + alloc((size_t)128 * 256 * 2));
    ushort* Wt1    = (ushort*)(w + alloc((size_t)128 * 128 * 2));
    ushort* Wt2    = (ushort*)(w + alloc((size_t)128 * 128 * 2));
    (void)ws_size; (void)n_in; (void)in_sizes; (void)out_size;

    hipMemsetAsync(cnt, 0, (size_t)N * 4, stream);

    deg_count_k<<<(E + 255) / 256, 256, 0, stream>>>(dst, cnt, E);
    bsum_k<<<SCAN_NB, 256, 0, stream>>>(cnt, bsum, N);
    bscan_k<<<1, 256, 0, stream>>>(bsum, boff, rp + N, SCAN_NB);
    scan3_k<<<SCAN_NB, 256, 0, stream>>>(cnt, boff, rp, dis, dinv, cursor, N);
    scatter_k<<<(E + 255) / 256, 256, 0, stream>>>(src, dst, rp, cursor, cew, dis, E);

    wtrans_all_k<<<256, 256, 0, stream>>>(W0, W1, W2, Wt0, Wt1, Wt2);

    int gemm_grid = (N + 63) / 64;
    int agg_grid  = (N + 3) / 4;

    // layer 0
    mfma_gemm_k<256, true><<<gemm_grid, 256, 0, stream>>>(x, Wt0, hb, N);
    aggregate_k<false><<<agg_grid, 256, 0, stream>>>(hb, rp, cew, dis, dinv, b0, act, out, N);
    // layer 1
    mfma_gemm_k<128, false><<<gemm_grid, 256, 0, stream>>>(act, Wt1, hb, N);
    aggregate_k<false><<<agg_grid, 256, 0, stream>>>(hb, rp, cew, dis, dinv, b1, act, out, N);
    // layer 2
    mfma_gemm_k<128, false><<<gemm_grid, 256, 0, stream>>>(act, Wt2, hb, N);
    aggregate_k<true><<<agg_grid, 256, 0, stream>>>(hb, rp, cew, dis, dinv, b2, act, out, N);
}